// Round 10
// baseline (91.745 us; speedup 1.0000x reference)
//
#include <hip/hip_runtime.h>
#include <math.h>

#define N 4096
#define D 64
#define NSLICE 8
#define JLEN 512          // N / NSLICE
#define CH 64             // j-chunk per iteration
#define NCHUNK 8          // JLEN / CH
#define SH 44.0f          // fixed softmax shift: exp(logit - 44); cancels in u/l

typedef short bf16x8 __attribute__((ext_vector_type(8)));
typedef float f32x4  __attribute__((ext_vector_type(4)));

__device__ __forceinline__ unsigned short f2bf(float x) {   // RNE f32->bf16
    unsigned int u = __float_as_uint(x);
    u += 0x7FFFu + ((u >> 16) & 1u);
    return (unsigned short)(u >> 16);
}
__device__ __forceinline__ float bf2f(unsigned short h) {
    return __uint_as_float(((unsigned int)h) << 16);
}

// Barrier that waits only LDS ops; global loads stay in flight across it.
__device__ __forceinline__ void lds_barrier() {
    asm volatile("s_waitcnt lgkmcnt(0)" ::: "memory");
    __builtin_amdgcn_s_barrier();
    asm volatile("" ::: "memory");
}

// ---------------- Kernel A: per-row scale + Mt[d][j] = bf16(linear(msg)) ----------------
__global__ __launch_bounds__(256) void prep_kernel(
    const float* __restrict__ embed,
    const float* __restrict__ degd, const float* __restrict__ degt,
    const float* __restrict__ W1, const float* __restrict__ b1,
    const float* __restrict__ W2, const float* __restrict__ b2,
    const float* __restrict__ W3, const float* __restrict__ b3,
    float* __restrict__ scale, unsigned short* __restrict__ Mt)
{
    const int rel = blockIdx.y;
    const float* W  = (rel == 0) ? W1 : (rel == 1 ? W2 : W3);
    const float* bb = (rel == 0) ? b1 : (rel == 1 ? b2 : b3);
    __shared__ float Wl[D][D + 1];
    __shared__ float xr[4][D];
    __shared__ unsigned short ot[4][D];   // staged Mt tile for coalesced write
    const int tid = threadIdx.x;
    for (int idx = tid; idx < D * D; idx += 256)
        Wl[idx >> 6][idx & 63] = W[idx];
    const int w = tid >> 6, d = tid & 63;
    const int i0 = blockIdx.x * 4;
    const int i = i0 + w;

    float msg, term, xsrc, dga, dgb;
    if (rel == 0) {
        float s = embed[(size_t)i * D + d];
        msg = s + s * s; term = s * msg; xsrc = msg;
        dga = degd[i]; dgb = degd[i];
    } else if (rel == 1) {
        float s = embed[(size_t)i * D + d];
        float t = embed[(size_t)(N + i) * D + d];
        msg = t + s * t; term = s * msg; xsrc = msg;
        dga = degd[i]; dgb = degt[i];
    } else {
        float t = embed[(size_t)(N + i) * D + d];
        msg = t + t * t; term = t * msg; xsrc = t;   // similar uses linear(task)!
        dga = degt[i]; dgb = degt[i];
    }
    float dot = term;
    #pragma unroll
    for (int mm = 1; mm < 64; mm <<= 1) dot += __shfl_xor(dot, mm);
    if (d == 0)
        scale[rel * N + i] = dot / (sqrtf(dga * dgb + 1e-8f) * 8.0f);  // sqrt(D)=8

    xr[w][d] = xsrc;
    __syncthreads();
    float o = bb[d];
    #pragma unroll 8
    for (int k = 0; k < D; ++k) o += xr[w][k] * Wl[d][k];
    ot[w][d] = f2bf(o);
    __syncthreads();
    // Mt[d][i0..i0+3]: 8B runs, one thread per d (wave 0 only)
    if (tid < 64) {
        union { unsigned short h[4]; uint2 v; } t;
        t.h[0] = ot[0][tid]; t.h[1] = ot[1][tid];
        t.h[2] = ot[2][tid]; t.h[3] = ot[3][tid];
        *(uint2*)&Mt[((size_t)rel * D + tid) * N + i0] = t.v;
    }
}

// ------------- Kernel B: fixed-shift softmax x (att @ M) via bf16 MFMA -------------
// grid (64 rowgroups, 3 rels, NSLICE slices), block 256 (4 waves), 4 blocks/CU.
// S and scale: direct global->reg loads (no LDS). Mt B-fragments: direct global
// 16B loads (L2-hot, transposed layout). LDS = double-buffered E only (16 KB).
// One lgkm-only barrier per chunk.
__global__ __launch_bounds__(256, 4) void attn_kernel(
    const float* __restrict__ S0, const float* __restrict__ S1, const float* __restrict__ S2,
    const float* __restrict__ scale, const unsigned short* __restrict__ Mt,
    unsigned short* __restrict__ Up, float* __restrict__ lp)
{
    __shared__ __align__(16) char EB[16384];   // E[2][8KB]: byte = cb*8192 + kg*1024 + ((row^kg)<<4)
    const int rg = blockIdx.x, rel = blockIdx.y, sl = blockIdx.z;
    const float* S = (rel == 0) ? S0 : (rel == 1 ? S1 : S2);
    const unsigned short* Mtr = Mt + (size_t)rel * D * N;
    const int tid = threadIdx.x;
    const int lane = tid & 63, wave = tid >> 6;
    const int row = tid >> 2, q = tid & 3;      // e-phase: 4 lanes/row, 16 cols each
    const int j0 = sl * JLEN;

    const float* Sp   = S + (size_t)(rg * 64 + row) * N + j0 + q * 16;
    const float* sclp = scale + rel * N + j0 + q * 16;

    const int wbase = wave * 16;
    const int lrow  = lane & 15;   // A-row / B-col / C-col within tile
    const int lk    = lane >> 4;   // k-octet within k-half / C row-group
    const unsigned short* bbp = Mtr + (size_t)lrow * N + j0 + lk * 8;

    float l = 0.f;
    f32x4 acc[4];
    #pragma unroll
    for (int ct = 0; ct < 4; ++ct) {
        acc[ct][0] = 0.f; acc[ct][1] = 0.f; acc[ct][2] = 0.f; acc[ct][3] = 0.f;
    }

    const int kgA = 2 * q, kgB = 2 * q + 1;
    char* ewA = EB + kgA * 1024 + ((row ^ kgA) << 4);
    char* ewB = EB + kgB * 1024 + ((row ^ kgB) << 4);

    #pragma unroll
    for (int c = 0; c < NCHUNK; ++c) {
        const int cb = (c & 1) * 8192;

        // ---- e-phase: direct global loads, exp, pack, 2x ds_write_b128 ----
        {
            const f32x4 s0 = *(const f32x4*)(Sp + c * CH + 0);
            const f32x4 s1 = *(const f32x4*)(Sp + c * CH + 4);
            const f32x4 s2 = *(const f32x4*)(Sp + c * CH + 8);
            const f32x4 s3 = *(const f32x4*)(Sp + c * CH + 12);
            const f32x4 c0 = *(const f32x4*)(sclp + c * CH + 0);
            const f32x4 c1 = *(const f32x4*)(sclp + c * CH + 4);
            const f32x4 c2 = *(const f32x4*)(sclp + c * CH + 8);
            const f32x4 c3 = *(const f32x4*)(sclp + c * CH + 12);
            float e[16];
            #pragma unroll
            for (int u = 0; u < 4; ++u) {
                e[u]      = __expf(fmaf(s0[u], c0[u], -SH));
                e[4 + u]  = __expf(fmaf(s1[u], c1[u], -SH));
                e[8 + u]  = __expf(fmaf(s2[u], c2[u], -SH));
                e[12 + u] = __expf(fmaf(s3[u], c3[u], -SH));
            }
            #pragma unroll
            for (int k = 0; k < 16; ++k) l += e[k];
            union { unsigned short h[8]; uint4 v; } p0, p1;
            #pragma unroll
            for (int k = 0; k < 8; ++k) { p0.h[k] = f2bf(e[k]); p1.h[k] = f2bf(e[8 + k]); }
            *(uint4*)(ewA + cb) = p0.v;
            *(uint4*)(ewB + cb) = p1.v;
        }

        lds_barrier();   // E visible to all waves

        // ---- MFMA: A from LDS E, B direct from global Mt (16B contiguous, L2-hot) ----
        #pragma unroll
        for (int ks = 0; ks < 2; ++ks) {
            const int kg = ks * 4 + lk;
            const bf16x8 a = *(const bf16x8*)(
                EB + cb + kg * 1024 + (((wbase + lrow) ^ kg) << 4));
            #pragma unroll
            for (int ct = 0; ct < 4; ++ct) {
                const bf16x8 b = *(const bf16x8*)(bbp + (size_t)ct * 16 * N + c * CH + ks * 32);
                acc[ct] = __builtin_amdgcn_mfma_f32_16x16x32_bf16(a, b, acc[ct], 0, 0, 0);
            }
        }
        // no second barrier: next iter writes the other E buffer; A-reads of this
        // buffer are register-complete before each wave reaches the next barrier.
    }

    // ---- epilogue: repack partials into E buffer 0 (all reads of it are done) ----
    unsigned short* R = (unsigned short*)EB;
    #pragma unroll
    for (int ct = 0; ct < 4; ++ct)
        #pragma unroll
        for (int r = 0; r < 4; ++r) {
            const int ri = wbase + lk * 4 + r;   // C/D: row=(lane>>4)*4+reg
            R[ri * 64 + ct * 16 + lrow] = f2bf(acc[ct][r]);
        }
    lds_barrier();
    const size_t pbase = (size_t)((rel * 64 + rg) * NSLICE + sl);
    unsigned short* up = Up + pbase * 4096;
    {
        const uint4* src = (const uint4*)R;
        uint4*       dst = (uint4*)up;
        dst[tid]       = src[tid];
        dst[256 + tid] = src[256 + tid];
    }
    l += __shfl_xor(l, 1);
    l += __shfl_xor(l, 2);
    if (q == 0) lp[pbase * 64 + row] = l;
}

// ---------------- Kernel C: combine partials + residual + linear(W3) + leaky-relu ----------------
__device__ __forceinline__ float combine_row(
    const unsigned short* __restrict__ Up, const float* __restrict__ lp,
    int rel, int i, int d)
{
    const int rg = i >> 6, r = i & 63;
    const int base = (rel * 64 + rg) * NSLICE;
    float lt = 0.f, u = 0.f;
    #pragma unroll
    for (int p = 0; p < NSLICE; ++p) {
        lt += lp[(base + p) * 64 + r];
        u  += bf2f(Up[(size_t)(base + p) * 4096 + r * 64 + d]);
    }
    return u / lt;   // fixed shift cancels; lt > 0 always
}

__global__ __launch_bounds__(256) void final_kernel(
    const float* __restrict__ embed,
    const unsigned short* __restrict__ Up, const float* __restrict__ lp,
    const float* __restrict__ W3, const float* __restrict__ b3,
    float* __restrict__ out)
{
    __shared__ float Wl[D][D + 1];
    __shared__ float xs[4][D];
    const int tid = threadIdx.x;
    for (int idx = tid; idx < D * D; idx += 256)
        Wl[idx >> 6][idx & 63] = W3[idx];
    const int w = tid >> 6, d = tid & 63;
    const int g = blockIdx.x * 4 + w;   // 0..8191

    float x = embed[(size_t)g * D + d];
    if (g < N) {
        x += combine_row(Up, lp, 0, g, d);
        x += combine_row(Up, lp, 1, g, d);
    } else {
        x += combine_row(Up, lp, 2, g - N, d);
    }
    xs[w][d] = x;
    __syncthreads();
    float o = b3[d];
    #pragma unroll 8
    for (int k = 0; k < D; ++k) o += xs[w][k] * Wl[d][k];
    o = (o > 0.f) ? o : 0.2f * o;
    out[(size_t)g * D + d] = o;
}

extern "C" void kernel_launch(void* const* d_in, const int* in_sizes, int n_in,
                              void* d_out, int out_size, void* d_ws, size_t ws_size,
                              hipStream_t stream)
{
    const float* embed = (const float*)d_in[0];
    // d_in[1..3] = adj_* (unused by the reference)
    const float* Sc   = (const float*)d_in[4];
    const float* Si   = (const float*)d_in[5];
    const float* Ss   = (const float*)d_in[6];
    const float* degd = (const float*)d_in[7];
    const float* degt = (const float*)d_in[8];
    const float* W1 = (const float*)d_in[9];
    const float* b1 = (const float*)d_in[10];
    const float* W2 = (const float*)d_in[11];
    const float* b2 = (const float*)d_in[12];
    const float* W3 = (const float*)d_in[13];
    const float* b3 = (const float*)d_in[14];
    float* out = (float*)d_out;

    // ws layout:
    //   scale: 3*N              = 12288 f32
    //   lp:    3*64*NSLICE*64   = 98304 f32
    //   Mt:    3*D*N            = 786432 ushort
    //   Up:    3*64*NSLICE*4096 = 6291456 ushort          total ~14.6 MB
    float* ws    = (float*)d_ws;
    float* scale = ws;
    float* lp    = ws + 12288;
    unsigned short* Mt = (unsigned short*)(lp + 98304);
    unsigned short* Up = Mt + 786432;

    prep_kernel<<<dim3(N / 4, 3), 256, 0, stream>>>(
        embed, degd, degt, W1, b1, W2, b2, W3, b3, scale, Mt);
    attn_kernel<<<dim3(64, 3, NSLICE), 256, 0, stream>>>(
        Sc, Si, Ss, scale, Mt, Up, lp);
    final_kernel<<<dim3(2 * N / 4), 256, 0, stream>>>(
        embed, Up, lp, W3, b3, out);
}

// Round 11
// 61.773 us; speedup vs baseline: 1.4852x; 1.4852x over previous
//
#include <hip/hip_runtime.h>
#include <math.h>

#define N 4096
#define D 64
#define NSLICE 8
#define JLEN 512          // N / NSLICE
#define CH 32             // j-chunk per iteration
#define NCHUNK 16         // JLEN / CH
#define SH 44.0f          // fixed softmax shift: exp(logit - 44); cancels in u/l

// LDS byte map (38 KB -> 4 blocks/CU):
//   S:   3 bufs x 8 KB  fp32 [64 rows][8 slots of 16B], slot ^= (row&7) via global pre-swizzle
//   Mt:  2 bufs x 4 KB  bf16, byte = kg*1024 + d*16   (kg = j-octet 0..3)
//   E:   4 KB           bf16, byte = q*1024 + ((row^q)<<4)
//   scl: 2 KB           fp32 scale slice
#define S_OFF   0
#define MT_OFF  24576
#define E_OFF   32768
#define SCL_OFF 36864
#define LDS_BYTES 38912

typedef short bf16x8 __attribute__((ext_vector_type(8)));
typedef float f32x4  __attribute__((ext_vector_type(4)));

__device__ __forceinline__ unsigned short f2bf(float x) {   // RNE f32->bf16
    unsigned int u = __float_as_uint(x);
    u += 0x7FFFu + ((u >> 16) & 1u);
    return (unsigned short)(u >> 16);
}
__device__ __forceinline__ float bf2f(unsigned short h) {
    return __uint_as_float(((unsigned int)h) << 16);
}

// async global->LDS DMA, 16B per lane; LDS dest wave-uniform base + lane*16.
__device__ __forceinline__ void gld16(const void* g, void* l) {
    __builtin_amdgcn_global_load_lds(
        (const __attribute__((address_space(1))) void*)g,
        (__attribute__((address_space(3))) void*)l,
        16, 0, 0);
}

// Barrier that waits only LDS ops; global/DMA loads stay in flight across it.
__device__ __forceinline__ void lds_barrier() {
    asm volatile("s_waitcnt lgkmcnt(0)" ::: "memory");
    __builtin_amdgcn_s_barrier();
    asm volatile("" ::: "memory");
}
__device__ __forceinline__ void plain_barrier() {
    asm volatile("" ::: "memory");
    __builtin_amdgcn_s_barrier();
    asm volatile("" ::: "memory");
}

// ---------------- Kernel A: per-row scale + Mt[d][j] = bf16(linear(msg)) ----------------
__global__ __launch_bounds__(256) void prep_kernel(
    const float* __restrict__ embed,
    const float* __restrict__ degd, const float* __restrict__ degt,
    const float* __restrict__ W1, const float* __restrict__ b1,
    const float* __restrict__ W2, const float* __restrict__ b2,
    const float* __restrict__ W3, const float* __restrict__ b3,
    float* __restrict__ scale, unsigned short* __restrict__ Mt)
{
    const int rel = blockIdx.y;
    const float* W  = (rel == 0) ? W1 : (rel == 1 ? W2 : W3);
    const float* bb = (rel == 0) ? b1 : (rel == 1 ? b2 : b3);
    __shared__ float Wl[D][D + 1];
    __shared__ float xr[4][D];
    __shared__ unsigned short ot[4][D];   // staged Mt tile for coalesced write
    const int tid = threadIdx.x;
    for (int idx = tid; idx < D * D; idx += 256)
        Wl[idx >> 6][idx & 63] = W[idx];
    const int w = tid >> 6, d = tid & 63;
    const int i0 = blockIdx.x * 4;
    const int i = i0 + w;

    float msg, term, xsrc, dga, dgb;
    if (rel == 0) {
        float s = embed[(size_t)i * D + d];
        msg = s + s * s; term = s * msg; xsrc = msg;
        dga = degd[i]; dgb = degd[i];
    } else if (rel == 1) {
        float s = embed[(size_t)i * D + d];
        float t = embed[(size_t)(N + i) * D + d];
        msg = t + s * t; term = s * msg; xsrc = msg;
        dga = degd[i]; dgb = degt[i];
    } else {
        float t = embed[(size_t)(N + i) * D + d];
        msg = t + t * t; term = t * msg; xsrc = t;   // similar uses linear(task)!
        dga = degt[i]; dgb = degt[i];
    }
    float dot = term;
    #pragma unroll
    for (int mm = 1; mm < 64; mm <<= 1) dot += __shfl_xor(dot, mm);
    if (d == 0)
        scale[rel * N + i] = dot / (sqrtf(dga * dgb + 1e-8f) * 8.0f);  // sqrt(D)=8

    xr[w][d] = xsrc;
    __syncthreads();
    float o = bb[d];
    #pragma unroll 8
    for (int k = 0; k < D; ++k) o += xr[w][k] * Wl[d][k];
    ot[w][d] = f2bf(o);
    __syncthreads();
    // Mt[d][i0..i0+3]: 8B runs, one thread per d (wave 0 only)
    if (tid < 64) {
        union { unsigned short h[4]; uint2 v; } t;
        t.h[0] = ot[0][tid]; t.h[1] = ot[1][tid];
        t.h[2] = ot[2][tid]; t.h[3] = ot[3][tid];
        *(uint2*)&Mt[((size_t)rel * D + tid) * N + i0] = t.v;
    }
}

// ------------- Kernel B: fixed-shift softmax x (att @ M) via bf16 MFMA -------------
// grid (64 rowgroups, 3 rels, NSLICE slices), block 256 (4 waves), 4 blocks/CU.
// DMA staging: S 3-buf (issue c+2 at top), Mt 2-buf (issue c+1 at top);
// FIFO-exact counted vmcnt(2) -- never drain in the main loop.
__global__ __launch_bounds__(256, 4) void attn_kernel(
    const float* __restrict__ S0, const float* __restrict__ S1, const float* __restrict__ S2,
    const float* __restrict__ scale, const unsigned short* __restrict__ Mt,
    unsigned short* __restrict__ Up, float* __restrict__ lp)
{
    __shared__ __align__(16) char LDS[LDS_BYTES];
    const int rg = blockIdx.x, rel = blockIdx.y, sl = blockIdx.z;
    const float* S = (rel == 0) ? S0 : (rel == 1 ? S1 : S2);
    const unsigned short* Mtr = Mt + (size_t)rel * D * N;
    const int tid = threadIdx.x;
    const int lane = tid & 63, wave = tid >> 6;
    const int row = tid >> 2, q = tid & 3;      // e-phase: 4 lanes/row, 8 cols each
    const int j0 = sl * JLEN;

    // S DMA mapping: thread tid -> (srow=tid>>3, sslot=tid&7); LDS byte tid*16.
    // Global pre-swizzled: slot_g = sslot ^ (srow&7).
    const int srow = tid >> 3, sslot = tid & 7;
    const int sx = (sslot ^ (srow & 7)) * 4;               // floats
    const float* s0p = S + (size_t)(rg * 64 + srow) * N + j0 + sx;
    const float* s1p = S + (size_t)(rg * 64 + 32 + srow) * N + j0 + sx;
    // Mt DMA: wave covers kg=wave, lane=d; dest byte = kg*1024 + d*16.
    const unsigned short* mtp = Mtr + (size_t)lane * N + j0 + wave * 8;
    char* sldsw = LDS + S_OFF + wave * 1024;   // + line*4096 + buf*8192
    char* mldsw = LDS + MT_OFF + wave * 1024;  // + buf*4096

#define ISSUE_S(cc, bb) do {                                       \
        gld16(s0p + (cc) * CH, sldsw + (bb) * 8192);               \
        gld16(s1p + (cc) * CH, sldsw + (bb) * 8192 + 4096);        \
    } while (0)
#define ISSUE_M(cc, bb) gld16(mtp + (cc) * CH, mldsw + (bb) * 4096)

    // prologue: stage scale slice; DMA queue [M0, S0a, S0b, S1a, S1b]
    {
        const f32x4 sc0 = *(const f32x4*)(scale + rel * N + j0 + tid * 2 - (tid & 1) * 4 + (tid & 1) * 4);
        (void)sc0;
    }
    for (int k = tid; k < JLEN; k += 256)
        *(float*)(LDS + SCL_OFF + k * 4) = scale[rel * N + j0 + k];
    asm volatile("" ::: "memory");
    ISSUE_M(0, 0);
    ISSUE_S(0, 0);
    ISSUE_S(1, 1);
    lds_barrier();   // scl visible; 5 DMAs in flight

    const int wbase = wave * 16;
    const int lrow  = lane & 15;   // A-row / B-col / C-col within tile
    const int lk    = lane >> 4;   // k-octet / C row-group
    float l = 0.f;
    f32x4 acc[4];
    #pragma unroll
    for (int ct = 0; ct < 4; ++ct) {
        acc[ct][0] = 0.f; acc[ct][1] = 0.f; acc[ct][2] = 0.f; acc[ct][3] = 0.f;
    }

    #pragma unroll
    for (int c = 0; c < NCHUNK; ++c) {
        // FIFO-exact: chunk c's [M,Sa,Sb] are the 3 oldest; keep the rest in flight
        if (c < NCHUNK - 1) asm volatile("s_waitcnt vmcnt(2)" ::: "memory");
        else                asm volatile("s_waitcnt vmcnt(0)" ::: "memory");
        plain_barrier();   // all waves' chunk-c data landed; prior readers done

        // issue M(c+1) (opposite Mt buf; its readers finished at this barrier),
        // then S(c+2) (buf (c+2)%3 = (c-1)%3; e-phase readers finished too)
        if (c + 1 < NCHUNK) ISSUE_M(c + 1, (c + 1) & 1);
        if (c + 2 < NCHUNK) { int t = c + 2; int b = t % 3; ISSUE_S(t, b); }

        // ---- e-phase: 8 cols/thread, exp, pack, one ds_write_b128 ----
        {
            const char* sb = LDS + S_OFF + (c % 3) * 8192 + row * 128;
            const int r7 = row & 7;
            const f32x4 sa = *(const f32x4*)(sb + (((2 * q)     ^ r7) << 4));
            const f32x4 sc = *(const f32x4*)(sb + (((2 * q + 1) ^ r7) << 4));
            const char* cb = LDS + SCL_OFF + c * 128 + q * 32;
            const f32x4 ca = *(const f32x4*)(cb);
            const f32x4 cc = *(const f32x4*)(cb + 16);
            float e[8];
            #pragma unroll
            for (int u = 0; u < 4; ++u) {
                e[u]     = __expf(fmaf(sa[u], ca[u], -SH));
                e[4 + u] = __expf(fmaf(sc[u], cc[u], -SH));
            }
            #pragma unroll
            for (int k = 0; k < 8; ++k) l += e[k];
            union { unsigned short h[8]; uint4 v; } pk;
            #pragma unroll
            for (int k = 0; k < 8; ++k) pk.h[k] = f2bf(e[k]);
            *(uint4*)(LDS + E_OFF + q * 1024 + ((row ^ q) << 4)) = pk.v;
        }

        lds_barrier();   // E visible; DMAs stay in flight

        // ---- MFMA: K=32, 4 col-tiles ----
        __builtin_amdgcn_s_setprio(1);
        {
            const char* mb = LDS + MT_OFF + (c & 1) * 4096 + lk * 1024;
            const bf16x8 a = *(const bf16x8*)(
                LDS + E_OFF + lk * 1024 + (((wbase + lrow) ^ lk) << 4));
            #pragma unroll
            for (int ct = 0; ct < 4; ++ct) {
                const bf16x8 b = *(const bf16x8*)(mb + ((ct * 16 + lrow) << 4));
                acc[ct] = __builtin_amdgcn_mfma_f32_16x16x32_bf16(a, b, acc[ct], 0, 0, 0);
            }
        }
        __builtin_amdgcn_s_setprio(0);
        // no trailing barrier: next iter's top barrier orders buffer reuse
    }
#undef ISSUE_S
#undef ISSUE_M

    // ---- epilogue: repack partials into S-buf region (dead), wide stores ----
    unsigned short* R = (unsigned short*)LDS;
    #pragma unroll
    for (int ct = 0; ct < 4; ++ct)
        #pragma unroll
        for (int r = 0; r < 4; ++r) {
            const int ri = wbase + lk * 4 + r;   // C/D: row=(lane>>4)*4+reg
            R[ri * 64 + ct * 16 + lrow] = f2bf(acc[ct][r]);
        }
    lds_barrier();
    const size_t pbase = (size_t)((rel * 64 + rg) * NSLICE + sl);
    unsigned short* up = Up + pbase * 4096;
    {
        const uint4* src = (const uint4*)R;
        uint4*       dst = (uint4*)up;
        dst[tid]       = src[tid];
        dst[256 + tid] = src[256 + tid];
    }
    l += __shfl_xor(l, 1);
    l += __shfl_xor(l, 2);
    if (q == 0) lp[pbase * 64 + row] = l;
}

// ---------------- Kernel C: combine partials + residual + linear(W3) + leaky-relu ----------------
__device__ __forceinline__ float combine_row(
    const unsigned short* __restrict__ Up, const float* __restrict__ lp,
    int rel, int i, int d)
{
    const int rg = i >> 6, r = i & 63;
    const int base = (rel * 64 + rg) * NSLICE;
    float lt = 0.f, u = 0.f;
    #pragma unroll
    for (int p = 0; p < NSLICE; ++p) {
        lt += lp[(base + p) * 64 + r];
        u  += bf2f(Up[(size_t)(base + p) * 4096 + r * 64 + d]);
    }
    return u / lt;   // fixed shift cancels; lt > 0 always
}

__global__ __launch_bounds__(256) void final_kernel(
    const float* __restrict__ embed,
    const unsigned short* __restrict__ Up, const float* __restrict__ lp,
    const float* __restrict__ W3, const float* __restrict__ b3,
    float* __restrict__ out)
{
    __shared__ float Wl[D][D + 1];
    __shared__ float xs[4][D];
    const int tid = threadIdx.x;
    for (int idx = tid; idx < D * D; idx += 256)
        Wl[idx >> 6][idx & 63] = W3[idx];
    const int w = tid >> 6, d = tid & 63;
    const int g = blockIdx.x * 4 + w;   // 0..8191

    float x = embed[(size_t)g * D + d];
    if (g < N) {
        x += combine_row(Up, lp, 0, g, d);
        x += combine_row(Up, lp, 1, g, d);
    } else {
        x += combine_row(Up, lp, 2, g - N, d);
    }
    xs[w][d] = x;
    __syncthreads();
    float o = b3[d];
    #pragma unroll 8
    for (int k = 0; k < D; ++k) o += xs[w][k] * Wl[d][k];
    o = (o > 0.f) ? o : 0.2f * o;
    out[(size_t)g * D + d] = o;
}

extern "C" void kernel_launch(void* const* d_in, const int* in_sizes, int n_in,
                              void* d_out, int out_size, void* d_ws, size_t ws_size,
                              hipStream_t stream)
{
    const float* embed = (const float*)d_in[0];
    // d_in[1..3] = adj_* (unused by the reference)
    const float* Sc   = (const float*)d_in[4];
    const float* Si   = (const float*)d_in[5];
    const float* Ss   = (const float*)d_in[6];
    const float* degd = (const float*)d_in[7];
    const float* degt = (const float*)d_in[8];
    const float* W1 = (const float*)d_in[9];
    const float* b1 = (const float*)d_in[10];
    const float* W2 = (const float*)d_in[11];
    const float* b2 = (const float*)d_in[12];
    const float* W3 = (const float*)d_in[13];
    const float* b3 = (const float*)d_in[14];
    float* out = (float*)d_out;

    // ws layout:
    //   scale: 3*N              = 12288 f32
    //   lp:    3*64*NSLICE*64   = 98304 f32
    //   Mt:    3*D*N            = 786432 ushort
    //   Up:    3*64*NSLICE*4096 = 6291456 ushort          total ~14.6 MB
    float* ws    = (float*)d_ws;
    float* scale = ws;
    float* lp    = ws + 12288;
    unsigned short* Mt = (unsigned short*)(lp + 98304);
    unsigned short* Up = Mt + 786432;

    prep_kernel<<<dim3(N / 4, 3), 256, 0, stream>>>(
        embed, degd, degt, W1, b1, W2, b2, W3, b3, scale, Mt);
    attn_kernel<<<dim3(64, 3, NSLICE), 256, 0, stream>>>(
        Sc, Si, Ss, scale, Mt, Up, lp);
    final_kernel<<<dim3(2 * N / 4), 256, 0, stream>>>(
        embed, Up, lp, W3, b3, out);
}